// Round 12
// baseline (282.200 us; speedup 1.0000x reference)
//
#include <hip/hip_runtime.h>
#include <hip/hip_fp16.h>

// ---------------------------------------------------------------------------
// EdgeClassifierGNN: 2x GCNConv (128->64->64, sym-norm, self-loops) + edge MLP
// Round 19: R18's uint4 k_agg was ~neutral-negative (279.8 vs 276.4; halved
// VMEM instrs but doubled csr_src chunk reloads) -> k_agg's 16-lane form is
// already full-row coalesced; the limit is latency x concurrency on random
// L2/L3 rows. Revert to R16's k_agg shape but raise occupancy: (256,4) ->
// (256,8) = 32 waves/CU, 2x outstanding gathers (footprint ~50 VGPR fits the
// 64-reg budget; falsifier: if spill -> FETCH balloons -> revert).
// Everything else identical to the 276.4us R16 config.
// ---------------------------------------------------------------------------

typedef float v4f __attribute__((ext_vector_type(4)));
typedef _Float16 v4h __attribute__((ext_vector_type(4)));

__device__ __forceinline__ float4 relu4(float4 v) {
    v.x = fmaxf(v.x, 0.f); v.y = fmaxf(v.y, 0.f);
    v.z = fmaxf(v.z, 0.f); v.w = fmaxf(v.w, 0.f);
    return v;
}

// async global -> LDS, 16B per lane
__device__ __forceinline__ void load_lds16(const void* g, void* l) {
    __builtin_amdgcn_global_load_lds(
        (const __attribute__((address_space(1))) void*)g,
        (__attribute__((address_space(3))) void*)l, 16, 0, 0);
}

// cnt[d]++ per edge; rank[e] = arrival order of e within its dst bucket
__global__ void k_count(const int* __restrict__ dst, int* __restrict__ cnt,
                        int* __restrict__ rank, int E) {
    int e = blockIdx.x * 256 + threadIdx.x;
    if (e < E) rank[e] = atomicAdd(&cnt[dst[e]], 1);
}

// block sums for scan + dinv = rsqrt(cnt+1) (fused)
__global__ void k_bsum(const int* __restrict__ cnt, int* __restrict__ bsum,
                       float* __restrict__ dinv, int N) {
    int i = blockIdx.x * 256 + threadIdx.x;
    int v = (i < N) ? cnt[i] : 0;
    if (i < N) dinv[i] = rsqrtf((float)v + 1.0f);
    int r = v;
#pragma unroll
    for (int d = 1; d < 64; d <<= 1) r += __shfl_xor(r, d);
    __shared__ int ws[4];
    if ((threadIdx.x & 63) == 0) ws[threadIdx.x >> 6] = r;
    __syncthreads();
    if (threadIdx.x == 0) bsum[blockIdx.x] = ws[0] + ws[1] + ws[2] + ws[3];
}

// in-place exclusive scan of bsum[0..nb), nb <= 256, single block
__global__ void k_scanb(int* __restrict__ bsum, int nb) {
    int t = threadIdx.x;
    int lane = t & 63, w = t >> 6;
    int v = (t < nb) ? bsum[t] : 0;
    int x = v;
#pragma unroll
    for (int d = 1; d < 64; d <<= 1) {
        int y = __shfl_up(x, d);
        if (lane >= d) x += y;
    }
    __shared__ int ws[4];
    if (lane == 63) ws[w] = x;
    __syncthreads();
    int woff = 0;
    for (int j = 0; j < w; j++) woff += ws[j];
    if (t < nb) bsum[t] = woff + x - v;
}

// row_ptr[i] = bsum[blk] + exclusive_scan_within_block(cnt); row_ptr[N] = E
__global__ void k_scan3(const int* __restrict__ cnt, const int* __restrict__ bsum,
                        int* __restrict__ row_ptr, int N, int E) {
    int t = threadIdx.x, b = blockIdx.x;
    int i = b * 256 + t;
    int lane = t & 63, w = t >> 6;
    int v = (i < N) ? cnt[i] : 0;
    int x = v;
#pragma unroll
    for (int d = 1; d < 64; d <<= 1) {
        int y = __shfl_up(x, d);
        if (lane >= d) x += y;
    }
    __shared__ int ws[4];
    if (lane == 63) ws[w] = x;
    __syncthreads();
    int woff = 0;
    for (int j = 0; j < w; j++) woff += ws[j];
    if (i < N) row_ptr[i] = bsum[b] + woff + x - v;
    if (i == 0) row_ptr[N] = E;
}

// atomic-free: csr_src[row_ptr[dst[e]] + rank[e]] = src[e]
__global__ void k_fill(const int* __restrict__ src, const int* __restrict__ dst,
                       const int* __restrict__ row_ptr, const int* __restrict__ rank,
                       int* __restrict__ csr_src, int E) {
    int e = blockIdx.x * 256 + threadIdx.x;
    if (e >= E) return;
    csr_src[row_ptr[dst[e]] + rank[e]] = src[e];
}

// MFMA GEMM: C[M x 64] = (SCALE? dinv[row]:1) * (op(A[M x K]) @ B[K x 64])
// (+bias on matrix 0 when NB==2). op = relu if RELU_A. fp16 inputs (converted
// at stage), fp32 accum, fp16 out. 64-row tiles, 4 waves. Fragment layout
// (proven): A[row=lane&15][k=4g+i], B[k=4g+i][col=lane&15] (weights staged
// TRANSPOSED: Bs[col][k]), D[row=4g+r][col=lane&15].
template<int K, bool RELU_A, bool SCALE, int NB>
__global__ __launch_bounds__(256) void k_mgemm(
    const float* __restrict__ A, const float* __restrict__ B0,
    const float* __restrict__ B1, const float* __restrict__ bias,
    const float* __restrict__ dinv, __half* __restrict__ C0,
    __half* __restrict__ C1, int M) {
    constexpr int P = K + 8;  // LDS pitch in halves (breaks pow2 bank stride)
    __shared__ __half As[64 * P];
    __shared__ __half Bs[NB * 64 * P];
    const int t = threadIdx.x;
    const int r0 = blockIdx.x * 64;

    // stage A tile (fp32 -> fp16, optional relu), contiguous 8B writes
    constexpr int C4 = K / 4;
    for (int idx = t; idx < 64 * C4; idx += 256) {
        int row = idx / C4, c4 = idx % C4;
        float4 v = make_float4(0.f, 0.f, 0.f, 0.f);
        if (r0 + row < M)
            v = reinterpret_cast<const float4*>(A + (size_t)(r0 + row) * K)[c4];
        if (RELU_A) v = relu4(v);
        __half* d = &As[row * P + 4 * c4];
        d[0] = __float2half(v.x); d[1] = __float2half(v.y);
        d[2] = __float2half(v.z); d[3] = __float2half(v.w);
    }
    // stage weights transposed: Bs[m][col][k]
    for (int m = 0; m < NB; m++) {
        const float* Bm = m ? B1 : B0;
        __half* Bsm = &Bs[m * 64 * P];
        for (int idx = t; idx < K * 16; idx += 256) {
            int k = idx >> 4, c4 = idx & 15;
            float4 v = reinterpret_cast<const float4*>(Bm + (size_t)k * 64)[c4];
            Bsm[(4 * c4 + 0) * P + k] = __float2half(v.x);
            Bsm[(4 * c4 + 1) * P + k] = __float2half(v.y);
            Bsm[(4 * c4 + 2) * P + k] = __float2half(v.z);
            Bsm[(4 * c4 + 3) * P + k] = __float2half(v.w);
        }
    }
    __syncthreads();

    const int lane = t & 63, w = t >> 6;
    const int li = lane & 15, g = lane >> 4;

    v4f acc[NB][4];
    const v4f zero = {0.f, 0.f, 0.f, 0.f};
#pragma unroll
    for (int m = 0; m < NB; m++)
#pragma unroll
        for (int c = 0; c < 4; c++) acc[m][c] = zero;

#pragma unroll
    for (int kk = 0; kk < K; kk += 16) {
        v4h a = *reinterpret_cast<const v4h*>(&As[(16 * w + li) * P + kk + 4 * g]);
#pragma unroll
        for (int m = 0; m < NB; m++) {
#pragma unroll
            for (int c = 0; c < 4; c++) {
                v4h b = *reinterpret_cast<const v4h*>(
                    &Bs[m * 64 * P + (16 * c + li) * P + kk + 4 * g]);
                acc[m][c] =
                    __builtin_amdgcn_mfma_f32_16x16x16f16(a, b, acc[m][c], 0, 0, 0);
            }
        }
    }

    // epilogue: lane holds rows rbase..rbase+3 at col 16c+li
    const int rbase = r0 + 16 * w + 4 * g;
    float sc[4] = {1.f, 1.f, 1.f, 1.f};
    if (SCALE) {
#pragma unroll
        for (int r = 0; r < 4; r++)
            sc[r] = (rbase + r < M) ? dinv[rbase + r] : 1.f;
    }
#pragma unroll
    for (int m = 0; m < NB; m++) {
        __half* C = m ? C1 : C0;
#pragma unroll
        for (int c = 0; c < 4; c++) {
            int col = 16 * c + li;
            float badd = (NB == 2 && m == 0) ? bias[col] : 0.f;
#pragma unroll
            for (int r = 0; r < 4; r++) {
                int gr = rbase + r;
                if (gr < M)
                    C[(size_t)gr * 64 + col] =
                        __float2half(acc[m][c][r] * sc[r] + badd);
            }
        }
    }
}

// 4 nodes/wave, 16 lanes/node, uint2 (4 fp16)/lane, 8-deep gather pipeline:
// out[d] = bias + dinv[d]*(A16[d] + sum_s A16[s]).
// (256,8): 32 waves/CU -- 2x outstanding gathers vs (256,4); footprint ~50
// VGPR fits the 64-reg budget (falsifier: spill -> FETCH balloons -> revert).
__global__ __launch_bounds__(256, 8) void k_agg(const __half* __restrict__ A16,
                                                const int* __restrict__ row_ptr,
                                                const int* __restrict__ csr_src,
                                                const float* __restrict__ dinv,
                                                const float* __restrict__ bias,
                                                float* __restrict__ out, int N) {
    int gw = (blockIdx.x * 256 + threadIdx.x) >> 6;  // global wave
    int sub = (threadIdx.x >> 4) & 3;
    int l = threadIdx.x & 15;
    int node = gw * 4 + sub;
    if (node >= N) return;
    const uint2* A4 = reinterpret_cast<const uint2*>(A16);  // row = 16 uint2

    int beg = row_ptr[node], end = row_ptr[node + 1];
    uint2 selfv = A4[(size_t)node * 16 + l];
    float2 a0 = __half22float2(*reinterpret_cast<__half2*>(&selfv.x));
    float2 a1 = __half22float2(*reinterpret_cast<__half2*>(&selfv.y));
    float4 acc = make_float4(a0.x, a0.y, a1.x, a1.y);

#define ACC(u)                                                          \
    {                                                                   \
        float2 f0 = __half22float2(*reinterpret_cast<__half2*>(&u.x));  \
        float2 f1 = __half22float2(*reinterpret_cast<__half2*>(&u.y));  \
        acc.x += f0.x; acc.y += f0.y; acc.z += f1.x; acc.w += f1.y;     \
    }
    for (int p = beg; p < end; p += 16) {
        int m = min(16, end - p);
        int sl = (p + l < end) ? csr_src[p + l] : 0;
        int j = 0;
        for (; j + 7 < m; j += 8) {
            uint2 u0 = A4[(size_t)__shfl(sl, j + 0, 16) * 16 + l];
            uint2 u1 = A4[(size_t)__shfl(sl, j + 1, 16) * 16 + l];
            uint2 u2 = A4[(size_t)__shfl(sl, j + 2, 16) * 16 + l];
            uint2 u3 = A4[(size_t)__shfl(sl, j + 3, 16) * 16 + l];
            uint2 u4 = A4[(size_t)__shfl(sl, j + 4, 16) * 16 + l];
            uint2 u5 = A4[(size_t)__shfl(sl, j + 5, 16) * 16 + l];
            uint2 u6 = A4[(size_t)__shfl(sl, j + 6, 16) * 16 + l];
            uint2 u7 = A4[(size_t)__shfl(sl, j + 7, 16) * 16 + l];
            ACC(u0) ACC(u1) ACC(u2) ACC(u3) ACC(u4) ACC(u5) ACC(u6) ACC(u7)
        }
        for (; j + 3 < m; j += 4) {
            uint2 u0 = A4[(size_t)__shfl(sl, j + 0, 16) * 16 + l];
            uint2 u1 = A4[(size_t)__shfl(sl, j + 1, 16) * 16 + l];
            uint2 u2 = A4[(size_t)__shfl(sl, j + 2, 16) * 16 + l];
            uint2 u3 = A4[(size_t)__shfl(sl, j + 3, 16) * 16 + l];
            ACC(u0) ACC(u1) ACC(u2) ACC(u3)
        }
        for (; j < m; j++) {
            uint2 u0 = A4[(size_t)__shfl(sl, j, 16) * 16 + l];
            ACC(u0)
        }
    }
#undef ACC
    float di = dinv[node];
    float4 bb = *reinterpret_cast<const float4*>(&bias[4 * l]);
    float4 o = make_float4(fmaf(di, acc.x, bb.x), fmaf(di, acc.y, bb.y),
                           fmaf(di, acc.z, bb.z), fmaf(di, acc.w, bb.w));
    *reinterpret_cast<float4*>(&out[(size_t)node * 64 + 4 * l]) = o;
}

// Edge epilogue via MFMA + LDS-staged endpoint rows, triple-buffered (R12).
// Per wave: 64 edges, 4 tiles of 16. Per tile: 32 endpoint rows (4KB) staged
// via 4x global_load_lds_dwordx4 (row-coalesced, source-side XOR swizzle).
// 2 tiles in flight (counted vmcnt 8/8/4/0); ea/sv/dv hoisted BEFORE stages
// (vmcnt is FIFO); stores deferred so vmcnt counts stay exact.
__global__ __launch_bounds__(256, 4) void k_edge(
    const __half* __restrict__ Ps, const __half* __restrict__ Pd,
    const int* __restrict__ src, const int* __restrict__ dst,
    const float* __restrict__ ea, const float* __restrict__ We,
    const float* __restrict__ Wm2, const float* __restrict__ bm2,
    float* __restrict__ out, int E) {
    __shared__ __align__(16) char smem[4 * 12288];  // 4 waves x 3 bufs x 4KB
    const int lane = threadIdx.x & 63;
    const int wid = (blockIdx.x * 256 + threadIdx.x) >> 6;
    const int li = lane & 15, g = lane >> 4;
    const int e0 = wid * 64;
    if (e0 >= E) return;

    char* wbase = smem + (threadIdx.x >> 6) * 12288;
    const float4* ea4 = reinterpret_cast<const float4*>(ea);  // row = 4 float4

    // A-frag (We^T): lane holds A[row=li][k=4g+i] of tile m -> We[4g+i][16m+li]
    v4h af[4];
#pragma unroll
    for (int m = 0; m < 4; m++) {
        v4h a;
#pragma unroll
        for (int i = 0; i < 4; i++)
            a[i] = (_Float16)We[(4 * g + i) * 64 + 16 * m + li];
        af[m] = a;
    }

    // Wm2 in the D layout: lane covers dims {16m+4g+r, r=0..3}
    float4 w2lo[4], w2hi[4];
#pragma unroll
    for (int m = 0; m < 4; m++) {
        int dim0 = 16 * m + 4 * g;
        w2lo[m] = *reinterpret_cast<const float4*>(&Wm2[2 * dim0]);      // rows r0,r1
        w2hi[m] = *reinterpret_cast<const float4*>(&Wm2[2 * dim0 + 4]);  // rows r2,r3
    }
    const float c0 = bm2[0], c1 = bm2[1];

    // per-lane edge indices (coalesced), redistributed by shfl
    const int ecl = min(e0 + lane, E - 1);
    const int sv = src[ecl], dv = dst[ecl];

    // hoist ea B-frags for all 4 tiles BEFORE staging (their conversion's
    // implicit vmcnt wait must not drain the stage queue)
    v4h bh[4];
#pragma unroll
    for (int n = 0; n < 4; n++) {
        int ee = min(e0 + 16 * n + li, E - 1);
        float4 bf = ea4[(size_t)ee * 4 + g];
        v4h t;
        t[0] = (_Float16)bf.x; t[1] = (_Float16)bf.y;
        t[2] = (_Float16)bf.z; t[3] = (_Float16)bf.w;
        bh[n] = t;
    }

    // staging lane decomposition: instr j writes rows 8j..8j+7, lane covers
    // (row = 8j + (l>>3), chunk16 = l&7); fetch global chunk (l&7)^(l>>3)
    const int jrow = lane >> 3;          // 0..7
    const int csw = (lane & 7) ^ jrow;   // pre-swizzled 16B chunk

#define STAGE(n, b)                                                              \
    {                                                                            \
        char* lb = wbase + (b) * 4096 + lane * 16;                               \
        int n0 = __shfl(sv, 16 * (n) + jrow);                                    \
        int n1 = __shfl(sv, 16 * (n) + 8 + jrow);                                \
        int n2 = __shfl(dv, 16 * (n) + jrow);                                    \
        int n3 = __shfl(dv, 16 * (n) + 8 + jrow);                                \
        load_lds16((const char*)Ps + (size_t)n0 * 128 + (csw << 4), lb);         \
        load_lds16((const char*)Ps + (size_t)n1 * 128 + (csw << 4), lb + 1024);  \
        load_lds16((const char*)Pd + (size_t)n2 * 128 + (csw << 4), lb + 2048);  \
        load_lds16((const char*)Pd + (size_t)n3 * 128 + (csw << 4), lb + 3072);  \
    }

    float p0s[4], p1s[4];

#define COMPUTE(n, b)                                                             \
    {                                                                             \
        const char* rb = wbase + (b) * 4096;                                      \
        uint2 us[4], ud[4];                                                       \
        _Pragma("unroll")                                                         \
        for (int m = 0; m < 4; m++) {                                             \
            int q = 4 * m + g;                                                    \
            int off = li * 128 + ((((q >> 1) ^ (li & 7)) << 4) | ((q & 1) << 3)); \
            us[m] = *reinterpret_cast<const uint2*>(rb + off);                    \
            ud[m] = *reinterpret_cast<const uint2*>(rb + 2048 + off);             \
        }                                                                         \
        float p0_ = 0.f, p1_ = 0.f;                                               \
        _Pragma("unroll")                                                         \
        for (int m = 0; m < 4; m++) {                                             \
            float2 s0 = __half22float2(*reinterpret_cast<__half2*>(&us[m].x));    \
            float2 s1 = __half22float2(*reinterpret_cast<__half2*>(&us[m].y));    \
            float2 d0 = __half22float2(*reinterpret_cast<__half2*>(&ud[m].x));    \
            float2 d1 = __half22float2(*reinterpret_cast<__half2*>(&ud[m].y));    \
            v4f c;                                                                \
            c[0] = s0.x + d0.x;                                                   \
            c[1] = s0.y + d0.y;                                                   \
            c[2] = s1.x + d1.x;                                                   \
            c[3] = s1.y + d1.y;                                                   \
            v4f q = __builtin_amdgcn_mfma_f32_16x16x16f16(af[m], bh[n], c, 0, 0, 0); \
            float u0 = fmaxf(q[0], 0.f), u1 = fmaxf(q[1], 0.f);                   \
            float u2 = fmaxf(q[2], 0.f), u3 = fmaxf(q[3], 0.f);                   \
            p0_ += u0 * w2lo[m].x + u1 * w2lo[m].z + u2 * w2hi[m].x + u3 * w2hi[m].z; \
            p1_ += u0 * w2lo[m].y + u1 * w2lo[m].w + u2 * w2hi[m].y + u3 * w2hi[m].w; \
        }                                                                         \
        p0_ += __shfl_xor(p0_, 16); p0_ += __shfl_xor(p0_, 32);                   \
        p1_ += __shfl_xor(p1_, 16); p1_ += __shfl_xor(p1_, 32);                   \
        p0s[n] = p0_; p1s[n] = p1_;                                               \
    }

    STAGE(0, 0)
    STAGE(1, 1)
    STAGE(2, 2)
    asm volatile("s_waitcnt vmcnt(8)" ::: "memory");   // stage 0 landed
    COMPUTE(0, 0)
    STAGE(3, 0)
    asm volatile("s_waitcnt vmcnt(8)" ::: "memory");   // stage 1 landed
    COMPUTE(1, 1)
    asm volatile("s_waitcnt vmcnt(4)" ::: "memory");   // stage 2 landed
    COMPUTE(2, 2)
    asm volatile("s_waitcnt vmcnt(0)" ::: "memory");   // stage 3 landed
    COMPUTE(3, 0)
#undef STAGE
#undef COMPUTE

    if (g == 0) {
#pragma unroll
        for (int n = 0; n < 4; n++) {
            int e = e0 + 16 * n + li;
            if (e < E)
                *reinterpret_cast<float2*>(&out[(size_t)e * 2]) =
                    make_float2(p0s[n] + c0, p1s[n] + c1);
        }
    }
}

static inline size_t align256(size_t x) { return (x + 255) & ~(size_t)255; }

extern "C" void kernel_launch(void* const* d_in, const int* in_sizes, int n_in,
                              void* d_out, int out_size, void* d_ws, size_t ws_size,
                              hipStream_t stream) {
    const float* x = (const float*)d_in[0];
    const int* ei = (const int*)d_in[1];
    const float* ea = (const float*)d_in[2];
    const float* W1 = (const float*)d_in[3];
    const float* b1 = (const float*)d_in[4];
    const float* W2 = (const float*)d_in[5];
    const float* b2 = (const float*)d_in[6];
    const float* Wm1 = (const float*)d_in[7];
    const float* bm1 = (const float*)d_in[8];
    const float* Wm2 = (const float*)d_in[9];
    const float* bm2 = (const float*)d_in[10];

    const int N = in_sizes[0] / 128;  // 50000
    const int E = in_sizes[1] / 2;    // 800000
    const int* src = ei;
    const int* dst = ei + E;
    float* out = (float*)d_out;

    const int NB = (N + 255) / 256;  // scan blocks (196)

    // ws layout (256B-aligned chunks)
    char* p = (char*)d_ws;
    int* cnt = (int*)p;        p += align256((size_t)N * 4);
    int* rank = (int*)p;       p += align256((size_t)E * 4);
    int* row_ptr = (int*)p;    p += align256((size_t)(N + 1) * 4);
    int* bsum = (int*)p;       p += align256((size_t)NB * 4);
    int* csr_src = (int*)p;    p += align256((size_t)E * 4);
    float* dinv = (float*)p;   p += align256((size_t)N * 4);
    __half* A16 = (__half*)p;  p += align256((size_t)N * 64 * 2);
    float* B = (float*)p;      p += align256((size_t)N * 64 * 4);
    __half* Ps16 = (__half*)p; p += align256((size_t)N * 64 * 2);
    __half* Pd16 = (__half*)p;

    // ---- CSR build (counting sort by dst; fill is atomic-free) ----
    hipMemsetAsync(cnt, 0, (size_t)N * sizeof(int), stream);
    k_count<<<(E + 255) / 256, 256, 0, stream>>>(dst, cnt, rank, E);
    k_bsum<<<NB, 256, 0, stream>>>(cnt, bsum, dinv, N);
    k_scanb<<<1, 256, 0, stream>>>(bsum, NB);
    k_scan3<<<NB, 256, 0, stream>>>(cnt, bsum, row_ptr, N, E);
    k_fill<<<(E + 255) / 256, 256, 0, stream>>>(src, dst, row_ptr, rank, csr_src, E);

    const int GB = (N + 63) / 64;    // 64-row GEMM tiles
    const int AB = (N + 15) / 16;    // 16 nodes/block (4 nodes/wave)

    // ---- Layer 1 ----
    k_mgemm<128, false, true, 1><<<GB, 256, 0, stream>>>(
        x, W1, nullptr, nullptr, dinv, A16, nullptr, N);
    k_agg<<<AB, 256, 0, stream>>>(A16, row_ptr, csr_src, dinv, b1, B, N);

    // ---- Layer 2 ----
    k_mgemm<64, true, true, 1><<<GB, 256, 0, stream>>>(
        B, W2, nullptr, nullptr, dinv, A16, nullptr, N);
    k_agg<<<AB, 256, 0, stream>>>(A16, row_ptr, csr_src, dinv, b2, B, N);

    // ---- Edge MLP, decomposed ----
    k_mgemm<64, true, false, 2><<<GB, 256, 0, stream>>>(
        B, Wm1, Wm1 + 64 * 64, bm1, nullptr, Ps16, Pd16, N);
    int waves = (E + 63) / 64;
    k_edge<<<(waves + 3) / 4, 256, 0, stream>>>(Ps16, Pd16, src, dst, ea,
                                                Wm1 + 128 * 64, Wm2, bm2,
                                                out, E);
}

// Round 13
// 276.607 us; speedup vs baseline: 1.0202x; 1.0202x over previous
//
#include <hip/hip_runtime.h>
#include <hip/hip_fp16.h>

// ---------------------------------------------------------------------------
// EdgeClassifierGNN: 2x GCNConv (128->64->64, sym-norm, self-loops) + edge MLP
// Round 20: REVERT to best-known (R16/R9 config, 276.4us). R19's (256,8)
// k_agg occupancy raise regressed (282.2) -- with R18 (wider loads, -3us),
// R15 (L2-resident split, -35us), R12 (deeper pipeline, neutral), every
// concurrency/width/locality lever on the gather kernels is now refuted:
// k_agg/k_edge sit at the hierarchy's random-128B-row request-service floor
// (~2.3-2.5 TB/s effective). GEMMs are MFMA'd, CSR is scan-limited, the 40us
// workspace poison-fill is harness-fixed. This file = R16 exactly.
// ---------------------------------------------------------------------------

typedef float v4f __attribute__((ext_vector_type(4)));
typedef _Float16 v4h __attribute__((ext_vector_type(4)));

__device__ __forceinline__ float4 relu4(float4 v) {
    v.x = fmaxf(v.x, 0.f); v.y = fmaxf(v.y, 0.f);
    v.z = fmaxf(v.z, 0.f); v.w = fmaxf(v.w, 0.f);
    return v;
}

// async global -> LDS, 16B per lane
__device__ __forceinline__ void load_lds16(const void* g, void* l) {
    __builtin_amdgcn_global_load_lds(
        (const __attribute__((address_space(1))) void*)g,
        (__attribute__((address_space(3))) void*)l, 16, 0, 0);
}

// cnt[d]++ per edge; rank[e] = arrival order of e within its dst bucket
__global__ void k_count(const int* __restrict__ dst, int* __restrict__ cnt,
                        int* __restrict__ rank, int E) {
    int e = blockIdx.x * 256 + threadIdx.x;
    if (e < E) rank[e] = atomicAdd(&cnt[dst[e]], 1);
}

// block sums for scan + dinv = rsqrt(cnt+1) (fused)
__global__ void k_bsum(const int* __restrict__ cnt, int* __restrict__ bsum,
                       float* __restrict__ dinv, int N) {
    int i = blockIdx.x * 256 + threadIdx.x;
    int v = (i < N) ? cnt[i] : 0;
    if (i < N) dinv[i] = rsqrtf((float)v + 1.0f);
    int r = v;
#pragma unroll
    for (int d = 1; d < 64; d <<= 1) r += __shfl_xor(r, d);
    __shared__ int ws[4];
    if ((threadIdx.x & 63) == 0) ws[threadIdx.x >> 6] = r;
    __syncthreads();
    if (threadIdx.x == 0) bsum[blockIdx.x] = ws[0] + ws[1] + ws[2] + ws[3];
}

// in-place exclusive scan of bsum[0..nb), nb <= 256, single block
__global__ void k_scanb(int* __restrict__ bsum, int nb) {
    int t = threadIdx.x;
    int lane = t & 63, w = t >> 6;
    int v = (t < nb) ? bsum[t] : 0;
    int x = v;
#pragma unroll
    for (int d = 1; d < 64; d <<= 1) {
        int y = __shfl_up(x, d);
        if (lane >= d) x += y;
    }
    __shared__ int ws[4];
    if (lane == 63) ws[w] = x;
    __syncthreads();
    int woff = 0;
    for (int j = 0; j < w; j++) woff += ws[j];
    if (t < nb) bsum[t] = woff + x - v;
}

// row_ptr[i] = bsum[blk] + exclusive_scan_within_block(cnt); row_ptr[N] = E
__global__ void k_scan3(const int* __restrict__ cnt, const int* __restrict__ bsum,
                        int* __restrict__ row_ptr, int N, int E) {
    int t = threadIdx.x, b = blockIdx.x;
    int i = b * 256 + t;
    int lane = t & 63, w = t >> 6;
    int v = (i < N) ? cnt[i] : 0;
    int x = v;
#pragma unroll
    for (int d = 1; d < 64; d <<= 1) {
        int y = __shfl_up(x, d);
        if (lane >= d) x += y;
    }
    __shared__ int ws[4];
    if (lane == 63) ws[w] = x;
    __syncthreads();
    int woff = 0;
    for (int j = 0; j < w; j++) woff += ws[j];
    if (i < N) row_ptr[i] = bsum[b] + woff + x - v;
    if (i == 0) row_ptr[N] = E;
}

// atomic-free: csr_src[row_ptr[dst[e]] + rank[e]] = src[e]
__global__ void k_fill(const int* __restrict__ src, const int* __restrict__ dst,
                       const int* __restrict__ row_ptr, const int* __restrict__ rank,
                       int* __restrict__ csr_src, int E) {
    int e = blockIdx.x * 256 + threadIdx.x;
    if (e >= E) return;
    csr_src[row_ptr[dst[e]] + rank[e]] = src[e];
}

// MFMA GEMM: C[M x 64] = (SCALE? dinv[row]:1) * (op(A[M x K]) @ B[K x 64])
// (+bias on matrix 0 when NB==2). op = relu if RELU_A. fp16 inputs (converted
// at stage), fp32 accum, fp16 out. 64-row tiles, 4 waves. Fragment layout
// (proven): A[row=lane&15][k=4g+i], B[k=4g+i][col=lane&15] (weights staged
// TRANSPOSED: Bs[col][k]), D[row=4g+r][col=lane&15].
template<int K, bool RELU_A, bool SCALE, int NB>
__global__ __launch_bounds__(256) void k_mgemm(
    const float* __restrict__ A, const float* __restrict__ B0,
    const float* __restrict__ B1, const float* __restrict__ bias,
    const float* __restrict__ dinv, __half* __restrict__ C0,
    __half* __restrict__ C1, int M) {
    constexpr int P = K + 8;  // LDS pitch in halves (breaks pow2 bank stride)
    __shared__ __half As[64 * P];
    __shared__ __half Bs[NB * 64 * P];
    const int t = threadIdx.x;
    const int r0 = blockIdx.x * 64;

    // stage A tile (fp32 -> fp16, optional relu), contiguous 8B writes
    constexpr int C4 = K / 4;
    for (int idx = t; idx < 64 * C4; idx += 256) {
        int row = idx / C4, c4 = idx % C4;
        float4 v = make_float4(0.f, 0.f, 0.f, 0.f);
        if (r0 + row < M)
            v = reinterpret_cast<const float4*>(A + (size_t)(r0 + row) * K)[c4];
        if (RELU_A) v = relu4(v);
        __half* d = &As[row * P + 4 * c4];
        d[0] = __float2half(v.x); d[1] = __float2half(v.y);
        d[2] = __float2half(v.z); d[3] = __float2half(v.w);
    }
    // stage weights transposed: Bs[m][col][k]
    for (int m = 0; m < NB; m++) {
        const float* Bm = m ? B1 : B0;
        __half* Bsm = &Bs[m * 64 * P];
        for (int idx = t; idx < K * 16; idx += 256) {
            int k = idx >> 4, c4 = idx & 15;
            float4 v = reinterpret_cast<const float4*>(Bm + (size_t)k * 64)[c4];
            Bsm[(4 * c4 + 0) * P + k] = __float2half(v.x);
            Bsm[(4 * c4 + 1) * P + k] = __float2half(v.y);
            Bsm[(4 * c4 + 2) * P + k] = __float2half(v.z);
            Bsm[(4 * c4 + 3) * P + k] = __float2half(v.w);
        }
    }
    __syncthreads();

    const int lane = t & 63, w = t >> 6;
    const int li = lane & 15, g = lane >> 4;

    v4f acc[NB][4];
    const v4f zero = {0.f, 0.f, 0.f, 0.f};
#pragma unroll
    for (int m = 0; m < NB; m++)
#pragma unroll
        for (int c = 0; c < 4; c++) acc[m][c] = zero;

#pragma unroll
    for (int kk = 0; kk < K; kk += 16) {
        v4h a = *reinterpret_cast<const v4h*>(&As[(16 * w + li) * P + kk + 4 * g]);
#pragma unroll
        for (int m = 0; m < NB; m++) {
#pragma unroll
            for (int c = 0; c < 4; c++) {
                v4h b = *reinterpret_cast<const v4h*>(
                    &Bs[m * 64 * P + (16 * c + li) * P + kk + 4 * g]);
                acc[m][c] =
                    __builtin_amdgcn_mfma_f32_16x16x16f16(a, b, acc[m][c], 0, 0, 0);
            }
        }
    }

    // epilogue: lane holds rows rbase..rbase+3 at col 16c+li
    const int rbase = r0 + 16 * w + 4 * g;
    float sc[4] = {1.f, 1.f, 1.f, 1.f};
    if (SCALE) {
#pragma unroll
        for (int r = 0; r < 4; r++)
            sc[r] = (rbase + r < M) ? dinv[rbase + r] : 1.f;
    }
#pragma unroll
    for (int m = 0; m < NB; m++) {
        __half* C = m ? C1 : C0;
#pragma unroll
        for (int c = 0; c < 4; c++) {
            int col = 16 * c + li;
            float badd = (NB == 2 && m == 0) ? bias[col] : 0.f;
#pragma unroll
            for (int r = 0; r < 4; r++) {
                int gr = rbase + r;
                if (gr < M)
                    C[(size_t)gr * 64 + col] =
                        __float2half(acc[m][c][r] * sc[r] + badd);
            }
        }
    }
}

// 4 nodes/wave, 16 lanes/node, uint2 (4 fp16)/lane, 8-deep gather pipeline:
// out[d] = bias + dinv[d]*(A16[d] + sum_s A16[s])
__global__ __launch_bounds__(256, 4) void k_agg(const __half* __restrict__ A16,
                                                const int* __restrict__ row_ptr,
                                                const int* __restrict__ csr_src,
                                                const float* __restrict__ dinv,
                                                const float* __restrict__ bias,
                                                float* __restrict__ out, int N) {
    int gw = (blockIdx.x * 256 + threadIdx.x) >> 6;  // global wave
    int sub = (threadIdx.x >> 4) & 3;
    int l = threadIdx.x & 15;
    int node = gw * 4 + sub;
    if (node >= N) return;
    const uint2* A4 = reinterpret_cast<const uint2*>(A16);  // row = 16 uint2

    int beg = row_ptr[node], end = row_ptr[node + 1];
    uint2 selfv = A4[(size_t)node * 16 + l];
    float2 a0 = __half22float2(*reinterpret_cast<__half2*>(&selfv.x));
    float2 a1 = __half22float2(*reinterpret_cast<__half2*>(&selfv.y));
    float4 acc = make_float4(a0.x, a0.y, a1.x, a1.y);

#define ACC(u)                                                          \
    {                                                                   \
        float2 f0 = __half22float2(*reinterpret_cast<__half2*>(&u.x));  \
        float2 f1 = __half22float2(*reinterpret_cast<__half2*>(&u.y));  \
        acc.x += f0.x; acc.y += f0.y; acc.z += f1.x; acc.w += f1.y;     \
    }
    for (int p = beg; p < end; p += 16) {
        int m = min(16, end - p);
        int sl = (p + l < end) ? csr_src[p + l] : 0;
        int j = 0;
        for (; j + 7 < m; j += 8) {
            uint2 u0 = A4[(size_t)__shfl(sl, j + 0, 16) * 16 + l];
            uint2 u1 = A4[(size_t)__shfl(sl, j + 1, 16) * 16 + l];
            uint2 u2 = A4[(size_t)__shfl(sl, j + 2, 16) * 16 + l];
            uint2 u3 = A4[(size_t)__shfl(sl, j + 3, 16) * 16 + l];
            uint2 u4 = A4[(size_t)__shfl(sl, j + 4, 16) * 16 + l];
            uint2 u5 = A4[(size_t)__shfl(sl, j + 5, 16) * 16 + l];
            uint2 u6 = A4[(size_t)__shfl(sl, j + 6, 16) * 16 + l];
            uint2 u7 = A4[(size_t)__shfl(sl, j + 7, 16) * 16 + l];
            ACC(u0) ACC(u1) ACC(u2) ACC(u3) ACC(u4) ACC(u5) ACC(u6) ACC(u7)
        }
        for (; j + 3 < m; j += 4) {
            uint2 u0 = A4[(size_t)__shfl(sl, j + 0, 16) * 16 + l];
            uint2 u1 = A4[(size_t)__shfl(sl, j + 1, 16) * 16 + l];
            uint2 u2 = A4[(size_t)__shfl(sl, j + 2, 16) * 16 + l];
            uint2 u3 = A4[(size_t)__shfl(sl, j + 3, 16) * 16 + l];
            ACC(u0) ACC(u1) ACC(u2) ACC(u3)
        }
        for (; j < m; j++) {
            uint2 u0 = A4[(size_t)__shfl(sl, j, 16) * 16 + l];
            ACC(u0)
        }
    }
#undef ACC
    float di = dinv[node];
    float4 bb = *reinterpret_cast<const float4*>(&bias[4 * l]);
    float4 o = make_float4(fmaf(di, acc.x, bb.x), fmaf(di, acc.y, bb.y),
                           fmaf(di, acc.z, bb.z), fmaf(di, acc.w, bb.w));
    *reinterpret_cast<float4*>(&out[(size_t)node * 64 + 4 * l]) = o;
}

// Edge epilogue via MFMA + LDS-staged endpoint rows, triple-buffered (R12).
// Per wave: 64 edges, 4 tiles of 16. Per tile: 32 endpoint rows (4KB) staged
// via 4x global_load_lds_dwordx4 (row-coalesced, source-side XOR swizzle).
// 2 tiles in flight (counted vmcnt 8/8/4/0); ea/sv/dv hoisted BEFORE stages
// (vmcnt is FIFO); stores deferred so vmcnt counts stay exact.
__global__ __launch_bounds__(256, 4) void k_edge(
    const __half* __restrict__ Ps, const __half* __restrict__ Pd,
    const int* __restrict__ src, const int* __restrict__ dst,
    const float* __restrict__ ea, const float* __restrict__ We,
    const float* __restrict__ Wm2, const float* __restrict__ bm2,
    float* __restrict__ out, int E) {
    __shared__ __align__(16) char smem[4 * 12288];  // 4 waves x 3 bufs x 4KB
    const int lane = threadIdx.x & 63;
    const int wid = (blockIdx.x * 256 + threadIdx.x) >> 6;
    const int li = lane & 15, g = lane >> 4;
    const int e0 = wid * 64;
    if (e0 >= E) return;

    char* wbase = smem + (threadIdx.x >> 6) * 12288;
    const float4* ea4 = reinterpret_cast<const float4*>(ea);  // row = 4 float4

    // A-frag (We^T): lane holds A[row=li][k=4g+i] of tile m -> We[4g+i][16m+li]
    v4h af[4];
#pragma unroll
    for (int m = 0; m < 4; m++) {
        v4h a;
#pragma unroll
        for (int i = 0; i < 4; i++)
            a[i] = (_Float16)We[(4 * g + i) * 64 + 16 * m + li];
        af[m] = a;
    }

    // Wm2 in the D layout: lane covers dims {16m+4g+r, r=0..3}
    float4 w2lo[4], w2hi[4];
#pragma unroll
    for (int m = 0; m < 4; m++) {
        int dim0 = 16 * m + 4 * g;
        w2lo[m] = *reinterpret_cast<const float4*>(&Wm2[2 * dim0]);      // rows r0,r1
        w2hi[m] = *reinterpret_cast<const float4*>(&Wm2[2 * dim0 + 4]);  // rows r2,r3
    }
    const float c0 = bm2[0], c1 = bm2[1];

    // per-lane edge indices (coalesced), redistributed by shfl
    const int ecl = min(e0 + lane, E - 1);
    const int sv = src[ecl], dv = dst[ecl];

    // hoist ea B-frags for all 4 tiles BEFORE staging (their conversion's
    // implicit vmcnt wait must not drain the stage queue)
    v4h bh[4];
#pragma unroll
    for (int n = 0; n < 4; n++) {
        int ee = min(e0 + 16 * n + li, E - 1);
        float4 bf = ea4[(size_t)ee * 4 + g];
        v4h t;
        t[0] = (_Float16)bf.x; t[1] = (_Float16)bf.y;
        t[2] = (_Float16)bf.z; t[3] = (_Float16)bf.w;
        bh[n] = t;
    }

    // staging lane decomposition: instr j writes rows 8j..8j+7, lane covers
    // (row = 8j + (l>>3), chunk16 = l&7); fetch global chunk (l&7)^(l>>3)
    const int jrow = lane >> 3;          // 0..7
    const int csw = (lane & 7) ^ jrow;   // pre-swizzled 16B chunk

#define STAGE(n, b)                                                              \
    {                                                                            \
        char* lb = wbase + (b) * 4096 + lane * 16;                               \
        int n0 = __shfl(sv, 16 * (n) + jrow);                                    \
        int n1 = __shfl(sv, 16 * (n) + 8 + jrow);                                \
        int n2 = __shfl(dv, 16 * (n) + jrow);                                    \
        int n3 = __shfl(dv, 16 * (n) + 8 + jrow);                                \
        load_lds16((const char*)Ps + (size_t)n0 * 128 + (csw << 4), lb);         \
        load_lds16((const char*)Ps + (size_t)n1 * 128 + (csw << 4), lb + 1024);  \
        load_lds16((const char*)Pd + (size_t)n2 * 128 + (csw << 4), lb + 2048);  \
        load_lds16((const char*)Pd + (size_t)n3 * 128 + (csw << 4), lb + 3072);  \
    }

    float p0s[4], p1s[4];

#define COMPUTE(n, b)                                                             \
    {                                                                             \
        const char* rb = wbase + (b) * 4096;                                      \
        uint2 us[4], ud[4];                                                       \
        _Pragma("unroll")                                                         \
        for (int m = 0; m < 4; m++) {                                             \
            int q = 4 * m + g;                                                    \
            int off = li * 128 + ((((q >> 1) ^ (li & 7)) << 4) | ((q & 1) << 3)); \
            us[m] = *reinterpret_cast<const uint2*>(rb + off);                    \
            ud[m] = *reinterpret_cast<const uint2*>(rb + 2048 + off);             \
        }                                                                         \
        float p0_ = 0.f, p1_ = 0.f;                                               \
        _Pragma("unroll")                                                         \
        for (int m = 0; m < 4; m++) {                                             \
            float2 s0 = __half22float2(*reinterpret_cast<__half2*>(&us[m].x));    \
            float2 s1 = __half22float2(*reinterpret_cast<__half2*>(&us[m].y));    \
            float2 d0 = __half22float2(*reinterpret_cast<__half2*>(&ud[m].x));    \
            float2 d1 = __half22float2(*reinterpret_cast<__half2*>(&ud[m].y));    \
            v4f c;                                                                \
            c[0] = s0.x + d0.x;                                                   \
            c[1] = s0.y + d0.y;                                                   \
            c[2] = s1.x + d1.x;                                                   \
            c[3] = s1.y + d1.y;                                                   \
            v4f q = __builtin_amdgcn_mfma_f32_16x16x16f16(af[m], bh[n], c, 0, 0, 0); \
            float u0 = fmaxf(q[0], 0.f), u1 = fmaxf(q[1], 0.f);                   \
            float u2 = fmaxf(q[2], 0.f), u3 = fmaxf(q[3], 0.f);                   \
            p0_ += u0 * w2lo[m].x + u1 * w2lo[m].z + u2 * w2hi[m].x + u3 * w2hi[m].z; \
            p1_ += u0 * w2lo[m].y + u1 * w2lo[m].w + u2 * w2hi[m].y + u3 * w2hi[m].w; \
        }                                                                         \
        p0_ += __shfl_xor(p0_, 16); p0_ += __shfl_xor(p0_, 32);                   \
        p1_ += __shfl_xor(p1_, 16); p1_ += __shfl_xor(p1_, 32);                   \
        p0s[n] = p0_; p1s[n] = p1_;                                               \
    }

    STAGE(0, 0)
    STAGE(1, 1)
    STAGE(2, 2)
    asm volatile("s_waitcnt vmcnt(8)" ::: "memory");   // stage 0 landed
    COMPUTE(0, 0)
    STAGE(3, 0)
    asm volatile("s_waitcnt vmcnt(8)" ::: "memory");   // stage 1 landed
    COMPUTE(1, 1)
    asm volatile("s_waitcnt vmcnt(4)" ::: "memory");   // stage 2 landed
    COMPUTE(2, 2)
    asm volatile("s_waitcnt vmcnt(0)" ::: "memory");   // stage 3 landed
    COMPUTE(3, 0)
#undef STAGE
#undef COMPUTE

    if (g == 0) {
#pragma unroll
        for (int n = 0; n < 4; n++) {
            int e = e0 + 16 * n + li;
            if (e < E)
                *reinterpret_cast<float2*>(&out[(size_t)e * 2]) =
                    make_float2(p0s[n] + c0, p1s[n] + c1);
        }
    }
}

static inline size_t align256(size_t x) { return (x + 255) & ~(size_t)255; }

extern "C" void kernel_launch(void* const* d_in, const int* in_sizes, int n_in,
                              void* d_out, int out_size, void* d_ws, size_t ws_size,
                              hipStream_t stream) {
    const float* x = (const float*)d_in[0];
    const int* ei = (const int*)d_in[1];
    const float* ea = (const float*)d_in[2];
    const float* W1 = (const float*)d_in[3];
    const float* b1 = (const float*)d_in[4];
    const float* W2 = (const float*)d_in[5];
    const float* b2 = (const float*)d_in[6];
    const float* Wm1 = (const float*)d_in[7];
    const float* bm1 = (const float*)d_in[8];
    const float* Wm2 = (const float*)d_in[9];
    const float* bm2 = (const float*)d_in[10];

    const int N = in_sizes[0] / 128;  // 50000
    const int E = in_sizes[1] / 2;    // 800000
    const int* src = ei;
    const int* dst = ei + E;
    float* out = (float*)d_out;

    const int NB = (N + 255) / 256;  // scan blocks (196)

    // ws layout (256B-aligned chunks)
    char* p = (char*)d_ws;
    int* cnt = (int*)p;        p += align256((size_t)N * 4);
    int* rank = (int*)p;       p += align256((size_t)E * 4);
    int* row_ptr = (int*)p;    p += align256((size_t)(N + 1) * 4);
    int* bsum = (int*)p;       p += align256((size_t)NB * 4);
    int* csr_src = (int*)p;    p += align256((size_t)E * 4);
    float* dinv = (float*)p;   p += align256((size_t)N * 4);
    __half* A16 = (__half*)p;  p += align256((size_t)N * 64 * 2);
    float* B = (float*)p;      p += align256((size_t)N * 64 * 4);
    __half* Ps16 = (__half*)p; p += align256((size_t)N * 64 * 2);
    __half* Pd16 = (__half*)p;

    // ---- CSR build (counting sort by dst; fill is atomic-free) ----
    hipMemsetAsync(cnt, 0, (size_t)N * sizeof(int), stream);
    k_count<<<(E + 255) / 256, 256, 0, stream>>>(dst, cnt, rank, E);
    k_bsum<<<NB, 256, 0, stream>>>(cnt, bsum, dinv, N);
    k_scanb<<<1, 256, 0, stream>>>(bsum, NB);
    k_scan3<<<NB, 256, 0, stream>>>(cnt, bsum, row_ptr, N, E);
    k_fill<<<(E + 255) / 256, 256, 0, stream>>>(src, dst, row_ptr, rank, csr_src, E);

    const int GB = (N + 63) / 64;    // 64-row GEMM tiles
    const int AB = (N + 15) / 16;    // 16 nodes/block (4 nodes/wave)

    // ---- Layer 1 ----
    k_mgemm<128, false, true, 1><<<GB, 256, 0, stream>>>(
        x, W1, nullptr, nullptr, dinv, A16, nullptr, N);
    k_agg<<<AB, 256, 0, stream>>>(A16, row_ptr, csr_src, dinv, b1, B, N);

    // ---- Layer 2 ----
    k_mgemm<64, true, true, 1><<<GB, 256, 0, stream>>>(
        B, W2, nullptr, nullptr, dinv, A16, nullptr, N);
    k_agg<<<AB, 256, 0, stream>>>(A16, row_ptr, csr_src, dinv, b2, B, N);

    // ---- Edge MLP, decomposed ----
    k_mgemm<64, true, false, 2><<<GB, 256, 0, stream>>>(
        B, Wm1, Wm1 + 64 * 64, bm1, nullptr, Ps16, Pd16, N);
    int waves = (E + 63) / 64;
    k_edge<<<(waves + 3) / 4, 256, 0, stream>>>(Ps16, Pd16, src, dst, ea,
                                                Wm1 + 128 * 64, Wm2, bm2,
                                                out, E);
}